// Round 1
// baseline (437.351 us; speedup 1.0000x reference)
//
#include <hip/hip_runtime.h>
#include <math.h>

// ConvCaps: A=B=32, C=D=16 (P=4), K=3, stride=2, pad=0, ITERS=3
// pose: [4][512][32][32] f32, W: [288][512][16] f32, out: [4][512][15][15] f32
#define AA 32
#define BB 32
#define CCDIM 16
#define DDIM 16
#define KKA 288
#define OH 15
#define OW 15
#define BATCH 4
#define NPOS 900          // 4 * 225
#define KCHUNKS 16
#define KPC 18            // 288 / 16
#define MT 16             // position tile: 15 valid (one oi row) + 1 pad

// ws layout (floats):
//   pbuf: [NPOS][KKA][16]            = 4,147,200
//   part: [KCHUNKS][NPOS][32][16]    = 7,372,800
//   V:    [NPOS][32][16]             =   460,800
#define PBUF_OFF 0
#define PART_OFF 4147200
#define V_OFF    (4147200 + 7372800)

// ---------------- unfold: pose -> pbuf[pos][k][c] ----------------
// block = (batch, a, oi); thread: x = t>>4 (oj), c = t&15
__global__ void unfold_k(const float* __restrict__ pose, float* __restrict__ pbuf)
{
    int blk = blockIdx.x;
    int oi = blk % OH;
    int a  = (blk / OH) % AA;
    int bt = blk / (OH * AA);
    int t = threadIdx.x;
    int x = t >> 4;          // oj
    int c = t & 15;
    if (x >= OW) return;
    int pos = bt * (OH * OW) + oi * OW + x;
    const float* src = pose + (((size_t)bt * 512 + a * 16 + c) * 32) * 32;
#pragma unroll
    for (int ki = 0; ki < 3; ++ki) {
        int ii = oi * 2 + ki;
#pragma unroll
        for (int kj = 0; kj < 3; ++kj) {
            int jj = x * 2 + kj;
            float v = src[ii * 32 + jj];
            int k = (ki * 3 + kj) * AA + a;
            pbuf[((size_t)pos * KKA + k) * 16 + c] = v;
        }
    }
}

// ---------------- routing pass (one per iteration) ----------------
// grid = 60 pos-tiles * 16 k-chunks. block 256.
// thread: b = t&31 (output capsule), dh = (t>>5)&1 (d half), mq = t>>6 (wave)
// each thread handles 4 positions m in {mq, mq+4, mq+8, mq+12}
template<int ITER>
__global__ __launch_bounds__(256) void route_k(const float* __restrict__ Wg,
                                               const float* __restrict__ pbuf,
                                               const float* __restrict__ Vbuf,
                                               float* __restrict__ part)
{
    __shared__ float4 Wlds[2048];                 // 32KB, XOR-swizzled W_k
    __shared__ __align__(16) float plds[MT][16];  // 1KB pose fragments

    const int wg = blockIdx.x;
    const int kc = wg % KCHUNKS;
    const int pt = wg / KCHUNKS;          // 0..59
    const int batch = pt / OH;
    const int oi = pt % OH;
    const int pos0 = batch * (OH * OW) + oi * OW;
    const int t = threadIdx.x;
    const int b  = t & 31;
    const int dh = (t >> 5) & 1;
    const int mq = t >> 6;

    // cumulative-v state (logits[k,b] = votes[k,b,:] . V[b,:])
    float V[4][8];
    if (ITER > 0) {
#pragma unroll
        for (int j = 0; j < 4; ++j) {
            int m = mq + j * 4;
            if (m < 15) {
                const float* vp = &Vbuf[(((size_t)(pos0 + m)) * 32 + b) * 16 + dh * 8];
                float4 q0 = *(const float4*)vp;
                float4 q1 = *(const float4*)(vp + 4);
                V[j][0] = q0.x; V[j][1] = q0.y; V[j][2] = q0.z; V[j][3] = q0.w;
                V[j][4] = q1.x; V[j][5] = q1.y; V[j][6] = q1.z; V[j][7] = q1.w;
            } else {
#pragma unroll
                for (int d = 0; d < 8; ++d) V[j][d] = 0.f;
            }
        }
    }

    float s[4][8];
#pragma unroll
    for (int j = 0; j < 4; ++j)
#pragma unroll
        for (int d = 0; d < 8; ++d) s[j][d] = 0.f;

    for (int kl = 0; kl < KPC; ++kl) {
        const int k = kc * KPC + kl;
        __syncthreads();
        // stage W_k, swizzled: float4 idx = b*64 + d*4 + c4, low 3 bits ^= (b&7)
        const float4* wsrc = (const float4*)(Wg + (size_t)k * 8192);
#pragma unroll
        for (int i = 0; i < 8; ++i) {
            int g = i * 256 + t;
            Wlds[g ^ ((g >> 6) & 7)] = wsrc[g];
        }
        // stage pose fragment for this k: plds[m][c]
        {
            int m = t >> 4, c = t & 15;
            float pv = 0.f;
            if (m < 15) pv = pbuf[(((size_t)(pos0 + m)) * KKA + k) * 16 + c];
            plds[m][c] = pv;
        }
        __syncthreads();

        // votes for (4 m) x (b) x (8 d of this half)
        float v[4][8];
#pragma unroll
        for (int j = 0; j < 4; ++j)
#pragma unroll
            for (int d = 0; d < 8; ++d) v[j][d] = 0.f;

#pragma unroll
        for (int c4 = 0; c4 < 4; ++c4) {
            float4 p4[4];
#pragma unroll
            for (int j = 0; j < 4; ++j)
                p4[j] = *(const float4*)&plds[mq + j * 4][c4 * 4];
#pragma unroll
            for (int dl = 0; dl < 8; ++dl) {
                int idx = b * 64 + (dh * 8 + dl) * 4 + c4;
                float4 w4 = Wlds[idx ^ (b & 7)];
#pragma unroll
                for (int j = 0; j < 4; ++j) {
                    v[j][dl] = fmaf(w4.x, p4[j].x,
                               fmaf(w4.y, p4[j].y,
                               fmaf(w4.z, p4[j].z,
                               fmaf(w4.w, p4[j].w, v[j][dl]))));
                }
            }
        }

        // routing weights c = softmax_b(votes . V)
        float cw[4];
        if (ITER == 0) {
#pragma unroll
            for (int j = 0; j < 4; ++j) cw[j] = 1.0f / 32.0f;
        } else {
#pragma unroll
            for (int j = 0; j < 4; ++j) {
                float lg = 0.f;
#pragma unroll
                for (int d = 0; d < 8; ++d) lg = fmaf(v[j][d], V[j][d], lg);
                lg += __shfl_xor(lg, 32, 64);   // combine d-halves (full 16-d dot)
                float mx = lg;
#pragma unroll
                for (int msk = 16; msk >= 1; msk >>= 1)
                    mx = fmaxf(mx, __shfl_xor(mx, msk, 64));
                float e = __expf(lg - mx);
                float su = e;
#pragma unroll
                for (int msk = 16; msk >= 1; msk >>= 1)
                    su += __shfl_xor(su, msk, 64);
                cw[j] = e / su;
            }
        }
#pragma unroll
        for (int j = 0; j < 4; ++j)
#pragma unroll
            for (int d = 0; d < 8; ++d)
                s[j][d] = fmaf(cw[j], v[j][d], s[j][d]);
    }

    // write per-k-chunk partial s
#pragma unroll
    for (int j = 0; j < 4; ++j) {
        int m = mq + j * 4;
        if (m < 15) {
            float* dst = &part[((((size_t)kc * NPOS) + pos0 + m) * 32 + b) * 16 + dh * 8];
            float4 q0 = { s[j][0], s[j][1], s[j][2], s[j][3] };
            float4 q1 = { s[j][4], s[j][5], s[j][6], s[j][7] };
            *(float4*)dst = q0;
            *(float4*)(dst + 4) = q1;
        }
    }
}

// ---------------- reduce partials + squash + V update / output ----------------
// grid = 900 (one block per position), block = 128: b = t>>2, d4 = t&3
template<int ITER>
__global__ void squash_k(const float* __restrict__ part,
                         float* __restrict__ Vbuf,
                         float* __restrict__ out)
{
    int pos = blockIdx.x;
    int t = threadIdx.x;
    int b = t >> 2, d4 = t & 3;
    float sx = 0.f, sy = 0.f, sz = 0.f, sw = 0.f;
#pragma unroll
    for (int kc = 0; kc < KCHUNKS; ++kc) {
        const float4 q = *(const float4*)&part[((((size_t)kc * NPOS) + pos) * 32 + b) * 16 + d4 * 4];
        sx += q.x; sy += q.y; sz += q.z; sw += q.w;
    }
    float n2 = sx * sx + sy * sy + sz * sz + sw * sw;
    n2 += __shfl_xor(n2, 1, 64);
    n2 += __shfl_xor(n2, 2, 64);    // full sum over 16 d (4 lanes per b)
    float scale = n2 / ((1.0f + n2) * sqrtf(n2 + 1e-8f));
    float vx = sx * scale, vy = sy * scale, vz = sz * scale, vw = sw * scale;

    if (ITER < 2) {
        float* Vp = &Vbuf[(((size_t)pos) * 32 + b) * 16 + d4 * 4];
        if (ITER == 0) {
            float4 q = { vx, vy, vz, vw };
            *(float4*)Vp = q;
        } else {
            float4 old = *(const float4*)Vp;
            float4 q = { old.x + vx, old.y + vy, old.z + vz, old.w + vw };
            *(float4*)Vp = q;
        }
    } else {
        // out[batch][b*16+d][oi][oj]
        int batch = pos / (OH * OW);
        int r = pos % (OH * OW);
        int oi = r / OW, oj = r % OW;
        size_t base = ((size_t)batch * 512 + b * 16 + d4 * 4) * (OH * OW) + oi * OW + oj;
        out[base]               = vx;
        out[base + 1 * OH * OW] = vy;
        out[base + 2 * OH * OW] = vz;
        out[base + 3 * OH * OW] = vw;
    }
}

extern "C" void kernel_launch(void* const* d_in, const int* in_sizes, int n_in,
                              void* d_out, int out_size, void* d_ws, size_t ws_size,
                              hipStream_t stream)
{
    const float* pose = (const float*)d_in[0];
    const float* Wg   = (const float*)d_in[1];
    float* out  = (float*)d_out;
    float* ws   = (float*)d_ws;
    float* pbuf = ws + PBUF_OFF;
    float* part = ws + PART_OFF;
    float* V    = ws + V_OFF;

    unfold_k<<<BATCH * AA * OH, 256, 0, stream>>>(pose, pbuf);

    route_k<0><<<60 * KCHUNKS, 256, 0, stream>>>(Wg, pbuf, V, part);
    squash_k<0><<<NPOS, 128, 0, stream>>>(part, V, out);

    route_k<1><<<60 * KCHUNKS, 256, 0, stream>>>(Wg, pbuf, V, part);
    squash_k<1><<<NPOS, 128, 0, stream>>>(part, V, out);

    route_k<2><<<60 * KCHUNKS, 256, 0, stream>>>(Wg, pbuf, V, part);
    squash_k<2><<<NPOS, 128, 0, stream>>>(part, V, out);
}

// Round 3
// 266.302 us; speedup vs baseline: 1.6423x; 1.6423x over previous
//
#include <hip/hip_runtime.h>
#include <math.h>

// ConvCaps: A=B=32, C=D=16, K=3, stride=2, ITERS=3
// pose: [4][512][32][32] f32, W: [288][512][16] f32, out: [4][512][15][15] f32
// pos = batch*225 + oi*15 + oj  (900 valid, padded to 928 = 29 tiles of 32)
#define KC   18      // k-chunks (parallelism axis)
#define KPC  16      // k per chunk (18*16 = 288)
#define NP   928
#define NPT  29

typedef __attribute__((ext_vector_type(8)))  short short8;   // 8 bf16 = 4 VGPR
typedef __attribute__((ext_vector_type(16))) float f32x16;   // MFMA C/D

__device__ __forceinline__ unsigned short f2bf(float x) {
    union { float f; unsigned u; } v; v.f = x;
    unsigned r = v.u + 0x7fffu + ((v.u >> 16) & 1u);
    return (unsigned short)(r >> 16);
}
__device__ __forceinline__ float bf2f(unsigned short h) {
    union { unsigned u; float f; } v; v.u = ((unsigned)h) << 16;
    return v.f;
}

// ---------------- W -> split bf16 (hi, lo) ----------------
// 288*512*16 = 2,359,296 elems; 4 per thread; grid 2304 x 256
__global__ void wprep(const float* __restrict__ W,
                      unsigned short* __restrict__ Whi,
                      unsigned short* __restrict__ Wlo)
{
    int idx = (blockIdx.x * 256 + threadIdx.x) * 4;
    float4 x = *(const float4*)(W + idx);
    ushort4 h, l;
    h.x = f2bf(x.x); l.x = f2bf(x.x - bf2f(h.x));
    h.y = f2bf(x.y); l.y = f2bf(x.y - bf2f(h.y));
    h.z = f2bf(x.z); l.z = f2bf(x.z - bf2f(h.z));
    h.w = f2bf(x.w); l.w = f2bf(x.w - bf2f(h.w));
    *(ushort4*)(Whi + idx) = h;
    *(ushort4*)(Wlo + idx) = l;
}

// ---------------- unfold pose -> split bf16 P[k][pos(928)][c(16)] ----------------
// grid = 288 * 58, block 256: c = t&15 (fastest -> coalesced writes), pos = chunk*16 + (t>>4)
__global__ void unfold(const float* __restrict__ pose,
                       unsigned short* __restrict__ Phi,
                       unsigned short* __restrict__ Plo)
{
    int bid = blockIdx.x;
    int k = bid / 58;
    int chunk = bid % 58;
    int t = threadIdx.x;
    int c = t & 15;
    int pos = chunk * 16 + (t >> 4);
    int a = k & 31;
    int kk = k >> 5;
    int ki = kk / 3, kj = kk % 3;
    float val = 0.f;
    if (pos < 900) {
        int batch = pos / 225;
        int rr = pos - batch * 225;
        int oi = rr / 15, oj = rr - (rr / 15) * 15;
        val = pose[(((size_t)batch * 512 + a * 16 + c) * 32 + (oi * 2 + ki)) * 32 + (oj * 2 + kj)];
    }
    unsigned short h = f2bf(val);
    unsigned short l = f2bf(val - bf2f(h));
    size_t o = ((size_t)k * NP + pos) * 16 + c;
    Phi[o] = h;
    Plo[o] = l;
}

// ---------------- routing pass ----------------
// grid = 29 pos-tiles * 18 k-chunks, block 512 = 8 waves.
// Swapped MFMA: D[bd(32-tile)][pos(32)] = W_k[bd][c] * p^T[c][pos] via mfma_32x32x16_bf16.
//   A frag: row = lane&31 (bd), c = (lane>>5)*8 + j
//   B frag: col = lane&31 (pos), c = (lane>>5)*8 + j
//   C/D  : col = lane&31 (pos), row(bd) = (reg&3) + 8*(reg>>2) + 4*(lane>>5)   [HW-verified]
// Wave w owns bd in [w*64, w*64+64) = 2 M-tiles = b in [w*4, w*4+4).
template<int ITER>
__global__ __launch_bounds__(512) void route(const unsigned short* __restrict__ Whi,
                                             const unsigned short* __restrict__ Wlo,
                                             const unsigned short* __restrict__ Phi,
                                             const unsigned short* __restrict__ Plo,
                                             const float* __restrict__ V,
                                             unsigned short* __restrict__ part)
{
    __shared__ float2 smb[2][8][32];   // [buf][wave][pos]: (wave max, wave expsum)

    const int bid = blockIdx.x;
    const int kc = bid % KC;
    const int pt = bid / KC;
    const int t = threadIdx.x;
    const int w = t >> 6;
    const int l = t & 63;
    const int col = l & 31;       // pos within tile
    const int h = l >> 5;
    const int gpos = pt * 32 + col;
    const int bd0 = w * 64;

    // V fragments (cumulative v), same layout as votes C-frag; loaded once.
    float vf[2][16];
    if constexpr (ITER > 0) {
        const float* vp = V + (size_t)gpos * 512 + bd0 + 4 * h;
#pragma unroll
        for (int m = 0; m < 2; ++m)
#pragma unroll
            for (int q = 0; q < 4; ++q) {
                float4 x = *(const float4*)(vp + m * 32 + 8 * q);
                vf[m][q * 4 + 0] = x.x; vf[m][q * 4 + 1] = x.y;
                vf[m][q * 4 + 2] = x.z; vf[m][q * 4 + 3] = x.w;
            }
    }

    f32x16 s[2];
#pragma unroll
    for (int m = 0; m < 2; ++m)
#pragma unroll
        for (int r = 0; r < 16; ++r) s[m][r] = 0.f;

    for (int kl = 0; kl < KPC; ++kl) {
        const int k = kc * KPC + kl;
        // A frags: W_k rows bd0+col and bd0+32+col, hi & lo
        size_t ab = ((size_t)k * 512 + bd0 + col) * 16 + 8 * h;
        short8 ah0 = *(const short8*)(Whi + ab);
        short8 ah1 = *(const short8*)(Whi + ab + 512);
        short8 al0 = *(const short8*)(Wlo + ab);
        short8 al1 = *(const short8*)(Wlo + ab + 512);
        // B frags: pose col for this position
        size_t bb = ((size_t)k * NP + gpos) * 16 + 8 * h;
        short8 bh = *(const short8*)(Phi + bb);
        short8 bl = *(const short8*)(Plo + bb);

        if constexpr (ITER == 0) {
            // uniform c = 1/32: accumulate votes directly across k
            s[0] = __builtin_amdgcn_mfma_f32_32x32x16_bf16(ah0, bh, s[0], 0, 0, 0);
            s[0] = __builtin_amdgcn_mfma_f32_32x32x16_bf16(ah0, bl, s[0], 0, 0, 0);
            s[0] = __builtin_amdgcn_mfma_f32_32x32x16_bf16(al0, bh, s[0], 0, 0, 0);
            s[1] = __builtin_amdgcn_mfma_f32_32x32x16_bf16(ah1, bh, s[1], 0, 0, 0);
            s[1] = __builtin_amdgcn_mfma_f32_32x32x16_bf16(ah1, bl, s[1], 0, 0, 0);
            s[1] = __builtin_amdgcn_mfma_f32_32x32x16_bf16(al1, bh, s[1], 0, 0, 0);
        } else {
            f32x16 v[2];
#pragma unroll
            for (int m = 0; m < 2; ++m)
#pragma unroll
                for (int r = 0; r < 16; ++r) v[m][r] = 0.f;
            v[0] = __builtin_amdgcn_mfma_f32_32x32x16_bf16(ah0, bh, v[0], 0, 0, 0);
            v[0] = __builtin_amdgcn_mfma_f32_32x32x16_bf16(ah0, bl, v[0], 0, 0, 0);
            v[0] = __builtin_amdgcn_mfma_f32_32x32x16_bf16(al0, bh, v[0], 0, 0, 0);
            v[1] = __builtin_amdgcn_mfma_f32_32x32x16_bf16(ah1, bh, v[1], 0, 0, 0);
            v[1] = __builtin_amdgcn_mfma_f32_32x32x16_bf16(ah1, bl, v[1], 0, 0, 0);
            v[1] = __builtin_amdgcn_mfma_f32_32x32x16_bf16(al1, bh, v[1], 0, 0, 0);

            // logits[pos, b] = sum_d votes * V ; b = w*4 + (m*2 + (q>>1))
            float lp[4] = {0.f, 0.f, 0.f, 0.f};
#pragma unroll
            for (int m = 0; m < 2; ++m)
#pragma unroll
                for (int q = 0; q < 4; ++q)
#pragma unroll
                    for (int i = 0; i < 4; ++i)
                        lp[m * 2 + (q >> 1)] = fmaf(v[m][q * 4 + i], vf[m][q * 4 + i],
                                                    lp[m * 2 + (q >> 1)]);
#pragma unroll
            for (int j = 0; j < 4; ++j) lp[j] += __shfl_xor(lp[j], 32);  // other d-half

            // wave-local softmax partial over this wave's 4 b's
            float mw = fmaxf(fmaxf(lp[0], lp[1]), fmaxf(lp[2], lp[3]));
            float ex[4], sw = 0.f;
#pragma unroll
            for (int j = 0; j < 4; ++j) { ex[j] = __expf(lp[j] - mw); sw += ex[j]; }
            if (h == 0) smb[kl & 1][w][col] = make_float2(mw, sw);
            __syncthreads();
            // combine 8 wave partials -> global max / denom for this pos
            float2 z[8];
            float M = -1e30f;
#pragma unroll
            for (int ww = 0; ww < 8; ++ww) { z[ww] = smb[kl & 1][ww][col]; M = fmaxf(M, z[ww].x); }
            float denom = 0.f;
#pragma unroll
            for (int ww = 0; ww < 8; ++ww) denom += z[ww].y * __expf(z[ww].x - M);
            float scale = __expf(mw - M) / denom;
            float cw[4];
#pragma unroll
            for (int j = 0; j < 4; ++j) cw[j] = ex[j] * scale;

            // s += c * votes
#pragma unroll
            for (int m = 0; m < 2; ++m)
#pragma unroll
                for (int q = 0; q < 4; ++q)
#pragma unroll
                    for (int i = 0; i < 4; ++i)
                        s[m][q * 4 + i] = fmaf(cw[m * 2 + (q >> 1)], v[m][q * 4 + i],
                                               s[m][q * 4 + i]);
        }
    }

    // write partial s (bf16), coalesced over pos: part[kc][bd][pos]
    const float mult = (ITER == 0) ? (1.0f / 32.0f) : 1.0f;
#pragma unroll
    for (int m = 0; m < 2; ++m)
#pragma unroll
        for (int q = 0; q < 4; ++q)
#pragma unroll
            for (int i = 0; i < 4; ++i) {
                int bd = bd0 + m * 32 + 8 * q + 4 * h + i;
                part[((size_t)(kc * 512 + bd)) * NP + gpos] = f2bf(s[m][q * 4 + i] * mult);
            }
}

// ---------------- reduce partials + squash ----------------
// grid = 29*4 = 116, block 256: pos = pt*32 + (t&31), b = bg*8 + (t>>5)
template<int ITER>
__global__ __launch_bounds__(256) void squash(const unsigned short* __restrict__ part,
                                              float* __restrict__ V,
                                              float* __restrict__ out)
{
    int bid = blockIdx.x;
    int pt = bid >> 2, bg = bid & 3;
    int t = threadIdx.x;
    int pos = pt * 32 + (t & 31);
    int b = bg * 8 + (t >> 5);

    float s[16];
#pragma unroll
    for (int d = 0; d < 16; ++d) s[d] = 0.f;
    for (int kc = 0; kc < KC; ++kc) {
        const unsigned short* pp = part + ((size_t)(kc * 512 + b * 16)) * NP + pos;
#pragma unroll
        for (int d = 0; d < 16; ++d) s[d] += bf2f(pp[(size_t)d * NP]);
    }
    float n2 = 0.f;
#pragma unroll
    for (int d = 0; d < 16; ++d) n2 = fmaf(s[d], s[d], n2);
    float scale = n2 / ((1.0f + n2) * sqrtf(n2 + 1e-8f));

    if constexpr (ITER < 2) {
        float* vp = V + (size_t)pos * 512 + b * 16;
#pragma unroll
        for (int d = 0; d < 16; ++d) {
            float val = s[d] * scale;
            if constexpr (ITER == 0) vp[d] = val;
            else                     vp[d] += val;
        }
    } else {
        if (pos < 900) {
            int batch = pos / 225;
            int opos = pos - batch * 225;
            float* op = out + ((size_t)(batch * 512 + b * 16)) * 225 + opos;
#pragma unroll
            for (int d = 0; d < 16; ++d) op[(size_t)d * 225] = s[d] * scale;
        }
    }
}

// ws layout (bytes):
//   Whi  @ 0          : 4,718,592
//   Wlo  @ 4,718,592  : 4,718,592
//   Phi  @ 9,437,184  : 8,552,448
//   Plo  @ 17,989,632 : 8,552,448
//   part @ 26,542,080 : 17,104,896   (bf16 [18][512][928])
//   V    @ 43,646,976 : 1,900,544    (f32  [928][512])
// total 45.5 MB  (< 47.9 MB proven available in round 0)
extern "C" void kernel_launch(void* const* d_in, const int* in_sizes, int n_in,
                              void* d_out, int out_size, void* d_ws, size_t ws_size,
                              hipStream_t stream)
{
    const float* pose = (const float*)d_in[0];
    const float* Wg   = (const float*)d_in[1];
    float* out = (float*)d_out;
    char* ws = (char*)d_ws;
    unsigned short* Whi  = (unsigned short*)(ws);
    unsigned short* Wlo  = (unsigned short*)(ws + 4718592);
    unsigned short* Phi  = (unsigned short*)(ws + 9437184);
    unsigned short* Plo  = (unsigned short*)(ws + 17989632);
    unsigned short* part = (unsigned short*)(ws + 26542080);
    float* V             = (float*)(ws + 43646976);

    wprep<<<2304, 256, 0, stream>>>(Wg, Whi, Wlo);
    unfold<<<288 * 58, 256, 0, stream>>>(pose, Phi, Plo);

    route<0><<<NPT * KC, 512, 0, stream>>>(Whi, Wlo, Phi, Plo, V, part);
    squash<0><<<116, 256, 0, stream>>>(part, V, out);
    route<1><<<NPT * KC, 512, 0, stream>>>(Whi, Wlo, Phi, Plo, V, part);
    squash<1><<<116, 256, 0, stream>>>(part, V, out);
    route<2><<<NPT * KC, 512, 0, stream>>>(Whi, Wlo, Phi, Plo, V, part);
    squash<2><<<116, 256, 0, stream>>>(part, V, out);
}

// Round 9
// 245.019 us; speedup vs baseline: 1.7850x; 1.0869x over previous
//
#include <hip/hip_runtime.h>
#include <math.h>

// ConvCaps: A=B=32, C=D=16, K=3, stride=2, ITERS=3
// pose: [4][512][32][32] f32, W: [288][512][16] f32, out: [4][512][15][15] f32
// pos = batch*225 + oi*15 + oj  (900 valid, padded to 928 = 29 tiles of 32)
#define KC   18      // k-chunks (parallelism axis)
#define KPC  16      // k per chunk (18*16 = 288)
#define NP   928
#define NPT  29

typedef __attribute__((ext_vector_type(8)))  short short8;   // 8 bf16 = 4 VGPR
typedef __attribute__((ext_vector_type(16))) float f32x16;   // MFMA C/D

__device__ __forceinline__ unsigned short f2bf(float x) {
    union { float f; unsigned u; } v; v.f = x;
    unsigned r = v.u + 0x7fffu + ((v.u >> 16) & 1u);
    return (unsigned short)(r >> 16);
}
__device__ __forceinline__ float bf2f(unsigned short h) {
    union { unsigned u; float f; } v; v.u = ((unsigned)h) << 16;
    return v.f;
}

// ---------------- W -> split bf16 (hi, lo) ----------------
__global__ void wprep(const float* __restrict__ W,
                      unsigned short* __restrict__ Whi,
                      unsigned short* __restrict__ Wlo)
{
    int idx = (blockIdx.x * 256 + threadIdx.x) * 4;
    float4 x = *(const float4*)(W + idx);
    ushort4 h, l;
    h.x = f2bf(x.x); l.x = f2bf(x.x - bf2f(h.x));
    h.y = f2bf(x.y); l.y = f2bf(x.y - bf2f(h.y));
    h.z = f2bf(x.z); l.z = f2bf(x.z - bf2f(h.z));
    h.w = f2bf(x.w); l.w = f2bf(x.w - bf2f(h.w));
    *(ushort4*)(Whi + idx) = h;
    *(ushort4*)(Wlo + idx) = l;
}

// ---------------- unfold pose -> split bf16 P[k][pos(928)][c(16)] ----------------
// block = (batch, a); stage 16 pose planes in LDS (row stride 33, plane 1057),
// then emit all 9 kernel-offset copies coalesced.
__global__ __launch_bounds__(256) void unfold(const float* __restrict__ pose,
                                              unsigned short* __restrict__ Phi,
                                              unsigned short* __restrict__ Plo)
{
    __shared__ float lds[16 * 1057];
    const int bid = blockIdx.x;          // 128 = 4 batch * 32 a
    const int batch = bid >> 5;
    const int a = bid & 31;
    const int t = threadIdx.x;

    const float* src = pose + ((size_t)batch * 512 + a * 16) * 1024;
#pragma unroll
    for (int c = 0; c < 16; ++c) {
        float4 v = *(const float4*)(src + c * 1024 + t * 4);
        float* d = &lds[c * 1057 + (t >> 3) * 33 + (t & 7) * 4];
        d[0] = v.x; d[1] = v.y; d[2] = v.z; d[3] = v.w;
    }
    __syncthreads();

    const int c = t & 15;
    const int px = t >> 4;
    for (int it = 0; it < 15; ++it) {
        int pos = it * 16 + px;
        bool ok = pos < 225;
        int pc = ok ? pos : 224;
        int oi = pc / 15, oj = pc - oi * 15;
#pragma unroll
        for (int ki = 0; ki < 3; ++ki)
#pragma unroll
            for (int kj = 0; kj < 3; ++kj) {
                float val = lds[c * 1057 + (oi * 2 + ki) * 33 + (oj * 2 + kj)];
                unsigned short hh = f2bf(val);
                unsigned short ll = f2bf(val - bf2f(hh));
                if (ok) {
                    size_t o = ((size_t)((ki * 3 + kj) * 32 + a) * NP
                                + batch * 225 + pos) * 16 + c;
                    Phi[o] = hh;
                    Plo[o] = ll;
                }
            }
    }
}

// ---------------- routing pass ----------------
// grid = 18 k-chunks (major) * 29 pos-tiles, block 512 = 8 waves.
// Swapped MFMA: D[bd(32-tile)][pos(32)] = W_k[bd][c] * p^T[c][pos], 32x32x16 bf16.
//   A frag: row = lane&31 (bd), c = (lane>>5)*8 + j
//   B frag: col = lane&31 (pos), c = (lane>>5)*8 + j
//   C/D  : col = lane&31 (pos), row(bd) = (reg&3) + 8*(reg>>2) + 4*(lane>>5)
// Wave w owns bd in [w*64, w*64+64).  Register-prefetch pipeline over k-steps;
// barrier drains LDS only (global prefetch stays in flight).
template<int ITER>
__global__ __launch_bounds__(512, 2) void route(const unsigned short* __restrict__ Whi,
                                                const unsigned short* __restrict__ Wlo,
                                                const unsigned short* __restrict__ Phi,
                                                const unsigned short* __restrict__ Plo,
                                                const float* __restrict__ V,
                                                unsigned short* __restrict__ part)
{
    __shared__ float2 smb[2][8][32];   // [buf][wave][pos]: (wave max, wave expsum)

    const int bid = blockIdx.x;
    const int pt = bid % NPT;          // kc-major: consecutive bids share W chunk
    const int kc = bid / NPT;
    const int t = threadIdx.x;
    const int w = t >> 6;
    const int l = t & 63;
    const int col = l & 31;            // pos within tile
    const int h = l >> 5;
    const int gpos = pt * 32 + col;
    const int bd0 = w * 64;

    float vf[2][16];
    if constexpr (ITER > 0) {
        const float* vp = V + (size_t)gpos * 512 + bd0 + 4 * h;
#pragma unroll
        for (int m = 0; m < 2; ++m)
#pragma unroll
            for (int q = 0; q < 4; ++q) {
                float4 x = *(const float4*)(vp + m * 32 + 8 * q);
                vf[m][q * 4 + 0] = x.x; vf[m][q * 4 + 1] = x.y;
                vf[m][q * 4 + 2] = x.z; vf[m][q * 4 + 3] = x.w;
            }
    }

    f32x16 s[2];
#pragma unroll
    for (int m = 0; m < 2; ++m)
#pragma unroll
        for (int r = 0; r < 16; ++r) s[m][r] = 0.f;

    // per-wave fragment stream pointers (k0 = kc*KPC)
    const size_t k0 = (size_t)kc * KPC;
    const unsigned short* pWh = Whi + (k0 * 512 + bd0 + col) * 16 + 8 * h;
    const unsigned short* pWl = Wlo + (k0 * 512 + bd0 + col) * 16 + 8 * h;
    const unsigned short* pPh = Phi + (k0 * NP + gpos) * 16 + 8 * h;
    const unsigned short* pPl = Plo + (k0 * NP + gpos) * 16 + 8 * h;

    short8 ah0 = *(const short8*)(pWh);
    short8 ah1 = *(const short8*)(pWh + 512);
    short8 al0 = *(const short8*)(pWl);
    short8 al1 = *(const short8*)(pWl + 512);
    short8 bh  = *(const short8*)(pPh);
    short8 bl  = *(const short8*)(pPl);

    for (int kl = 0; kl < KPC; ++kl) {
        // prefetch next step's frags (last step reads 8KB past — still inside ws)
        const int nw = (kl + 1) * 8192;      // 512*16 shorts per k
        const int np = (kl + 1) * 14848;     // NP*16 shorts per k
        short8 nah0 = *(const short8*)(pWh + nw);
        short8 nah1 = *(const short8*)(pWh + nw + 512);
        short8 nal0 = *(const short8*)(pWl + nw);
        short8 nal1 = *(const short8*)(pWl + nw + 512);
        short8 nbh  = *(const short8*)(pPh + np);
        short8 nbl  = *(const short8*)(pPl + np);

        if constexpr (ITER == 0) {
            s[0] = __builtin_amdgcn_mfma_f32_32x32x16_bf16(ah0, bh, s[0], 0, 0, 0);
            s[1] = __builtin_amdgcn_mfma_f32_32x32x16_bf16(ah1, bh, s[1], 0, 0, 0);
            s[0] = __builtin_amdgcn_mfma_f32_32x32x16_bf16(ah0, bl, s[0], 0, 0, 0);
            s[1] = __builtin_amdgcn_mfma_f32_32x32x16_bf16(ah1, bl, s[1], 0, 0, 0);
            s[0] = __builtin_amdgcn_mfma_f32_32x32x16_bf16(al0, bh, s[0], 0, 0, 0);
            s[1] = __builtin_amdgcn_mfma_f32_32x32x16_bf16(al1, bh, s[1], 0, 0, 0);
        } else {
            f32x16 v[2];
#pragma unroll
            for (int m = 0; m < 2; ++m)
#pragma unroll
                for (int r = 0; r < 16; ++r) v[m][r] = 0.f;
            v[0] = __builtin_amdgcn_mfma_f32_32x32x16_bf16(ah0, bh, v[0], 0, 0, 0);
            v[1] = __builtin_amdgcn_mfma_f32_32x32x16_bf16(ah1, bh, v[1], 0, 0, 0);
            v[0] = __builtin_amdgcn_mfma_f32_32x32x16_bf16(ah0, bl, v[0], 0, 0, 0);
            v[1] = __builtin_amdgcn_mfma_f32_32x32x16_bf16(ah1, bl, v[1], 0, 0, 0);
            v[0] = __builtin_amdgcn_mfma_f32_32x32x16_bf16(al0, bh, v[0], 0, 0, 0);
            v[1] = __builtin_amdgcn_mfma_f32_32x32x16_bf16(al1, bh, v[1], 0, 0, 0);

            // logits[pos, b] = votes . V ;  b = w*4 + (m*2 + (q>>1))
            float lp[4] = {0.f, 0.f, 0.f, 0.f};
#pragma unroll
            for (int m = 0; m < 2; ++m)
#pragma unroll
                for (int q = 0; q < 4; ++q)
#pragma unroll
                    for (int i = 0; i < 4; ++i)
                        lp[m * 2 + (q >> 1)] = fmaf(v[m][q * 4 + i], vf[m][q * 4 + i],
                                                    lp[m * 2 + (q >> 1)]);
#pragma unroll
            for (int j = 0; j < 4; ++j) lp[j] += __shfl_xor(lp[j], 32);

            // wave-local softmax partial over this wave's 4 b's
            float mw = fmaxf(fmaxf(lp[0], lp[1]), fmaxf(lp[2], lp[3]));
            float ex[4], sw = 0.f;
#pragma unroll
            for (int j = 0; j < 4; ++j) { ex[j] = __expf(lp[j] - mw); sw += ex[j]; }
            if (h == 0) smb[kl & 1][w][col] = make_float2(mw, sw);
            // LDS-only drain + barrier: global prefetch stays in flight
            asm volatile("s_waitcnt lgkmcnt(0)\n\ts_barrier" ::: "memory");
            float2 z[8];
            float M = -1e30f;
#pragma unroll
            for (int ww = 0; ww < 8; ++ww) { z[ww] = smb[kl & 1][ww][col]; M = fmaxf(M, z[ww].x); }
            float denom = 0.f;
#pragma unroll
            for (int ww = 0; ww < 8; ++ww) denom += z[ww].y * __expf(z[ww].x - M);
            float scale = __expf(mw - M) / denom;
            float cw[4];
#pragma unroll
            for (int j = 0; j < 4; ++j) cw[j] = ex[j] * scale;

#pragma unroll
            for (int m = 0; m < 2; ++m)
#pragma unroll
                for (int q = 0; q < 4; ++q)
#pragma unroll
                    for (int i = 0; i < 4; ++i)
                        s[m][q * 4 + i] = fmaf(cw[m * 2 + (q >> 1)], v[m][q * 4 + i],
                                               s[m][q * 4 + i]);
        }

        ah0 = nah0; ah1 = nah1; al0 = nal0; al1 = nal1; bh = nbh; bl = nbl;
    }

    // write partial s (bf16), coalesced over pos: part[kc][bd][pos]
    const float mult = (ITER == 0) ? (1.0f / 32.0f) : 1.0f;
#pragma unroll
    for (int m = 0; m < 2; ++m)
#pragma unroll
        for (int q = 0; q < 4; ++q)
#pragma unroll
            for (int i = 0; i < 4; ++i) {
                int bd = bd0 + m * 32 + 8 * q + 4 * h + i;
                part[((size_t)(kc * 512 + bd)) * NP + gpos] = f2bf(s[m][q * 4 + i] * mult);
            }
}

// ---------------- reduce partials + squash ----------------
template<int ITER>
__global__ __launch_bounds__(256) void squash(const unsigned short* __restrict__ part,
                                              float* __restrict__ V,
                                              float* __restrict__ out)
{
    int bid = blockIdx.x;
    int pt = bid >> 2, bg = bid & 3;
    int t = threadIdx.x;
    int pos = pt * 32 + (t & 31);
    int b = bg * 8 + (t >> 5);

    float s[16];
#pragma unroll
    for (int d = 0; d < 16; ++d) s[d] = 0.f;
    for (int kc = 0; kc < KC; ++kc) {
        const unsigned short* pp = part + ((size_t)(kc * 512 + b * 16)) * NP + pos;
#pragma unroll
        for (int d = 0; d < 16; ++d) s[d] += bf2f(pp[(size_t)d * NP]);
    }
    float n2 = 0.f;
#pragma unroll
    for (int d = 0; d < 16; ++d) n2 = fmaf(s[d], s[d], n2);
    float scale = n2 / ((1.0f + n2) * sqrtf(n2 + 1e-8f));

    if constexpr (ITER < 2) {
        float* vp = V + (size_t)pos * 512 + b * 16;
#pragma unroll
        for (int d = 0; d < 16; ++d) {
            float val = s[d] * scale;
            if constexpr (ITER == 0) vp[d] = val;
            else                     vp[d] += val;
        }
    } else {
        if (pos < 900) {
            int batch = pos / 225;
            int opos = pos - batch * 225;
            float* op = out + ((size_t)(batch * 512 + b * 16)) * 225 + opos;
#pragma unroll
            for (int d = 0; d < 16; ++d) op[(size_t)d * 225] = s[d] * scale;
        }
    }
}

// ws layout (bytes):
//   Whi  @ 0          : 4,718,592
//   Wlo  @ 4,718,592  : 4,718,592
//   Phi  @ 9,437,184  : 8,552,448
//   Plo  @ 17,989,632 : 8,552,448
//   part @ 26,542,080 : 17,104,896   (bf16 [18][512][928])
//   V    @ 43,646,976 : 1,900,544    (f32  [928][512])
// total 45.5 MB
extern "C" void kernel_launch(void* const* d_in, const int* in_sizes, int n_in,
                              void* d_out, int out_size, void* d_ws, size_t ws_size,
                              hipStream_t stream)
{
    const float* pose = (const float*)d_in[0];
    const float* Wg   = (const float*)d_in[1];
    float* out = (float*)d_out;
    char* ws = (char*)d_ws;
    unsigned short* Whi  = (unsigned short*)(ws);
    unsigned short* Wlo  = (unsigned short*)(ws + 4718592);
    unsigned short* Phi  = (unsigned short*)(ws + 9437184);
    unsigned short* Plo  = (unsigned short*)(ws + 17989632);
    unsigned short* part = (unsigned short*)(ws + 26542080);
    float* V             = (float*)(ws + 43646976);

    wprep<<<2304, 256, 0, stream>>>(Wg, Whi, Wlo);
    unfold<<<128, 256, 0, stream>>>(pose, Phi, Plo);

    route<0><<<NPT * KC, 512, 0, stream>>>(Whi, Wlo, Phi, Plo, V, part);
    squash<0><<<116, 256, 0, stream>>>(part, V, out);
    route<1><<<NPT * KC, 512, 0, stream>>>(Whi, Wlo, Phi, Plo, V, part);
    squash<1><<<116, 256, 0, stream>>>(part, V, out);
    route<2><<<NPT * KC, 512, 0, stream>>>(Whi, Wlo, Phi, Plo, V, part);
    squash<2><<<116, 256, 0, stream>>>(part, V, out);
}